// Round 9
// baseline (2701.513 us; speedup 1.0000x reference)
//
#include <hip/hip_runtime.h>
#include <stdint.h>

#define SLEN    512
#define IDIM    256
#define HDIM    512
#define NROW    256          // 2 sequences x 128 batch rows
#define HPH     520          // h LDS row stride in halfs (512+8): 2-way banks
#define XPF     260          // x LDS row stride in floats (256+4): 2-way banks
#define NSTEP   512
#define NGRP    16           // batch groups (16 rows each)
#define GWG     16           // WGs (column groups) per batch group

typedef __attribute__((ext_vector_type(8))) _Float16 half8;
typedef __attribute__((ext_vector_type(4))) float   f32x4;

#define AS1 __attribute__((address_space(1)))
#define AS3 __attribute__((address_space(3)))

__device__ __forceinline__ float sigm(float x)   { return 1.0f / (1.0f + __expf(-x)); }
__device__ __forceinline__ float tanh_f(float x) { return 2.0f / (1.0f + __expf(-2.0f * x)) - 1.0f; }

__device__ __forceinline__ half8 cvt8(float4 a, float4 b) {
    half8 v;
    v[0] = (_Float16)a.x; v[1] = (_Float16)a.y; v[2] = (_Float16)a.z; v[3] = (_Float16)a.w;
    v[4] = (_Float16)b.x; v[5] = (_Float16)b.y; v[6] = (_Float16)b.z; v[7] = (_Float16)b.w;
    return v;
}

union hu { _Float16 h; unsigned short u; };

// Round-9: producer/consumer WAVE SPECIALIZATION. 320 threads = 4 compute
// waves + 1 sync wave per WG.
// R6/R8 post-mortem: best-case serial chain ~3500cy but measured ~7000cy —
// the gap is flag-detection latency + LLC burst queueing, amplified by
// in-order vmcnt (compute polls drained behind their own store-acks).
//  - sync wave (w==4): poll 64 group flags -> issue ALL h-DMAs (16) and
//    x(t+1)-DMAs (16) -> vmcnt(0) -> s_barrier. Pure-load queue; polls run
//    WHILE compute waves do hGEMM/cell/store/xGEMM (~2000cy window), so
//    detection + h-load RT are off the compute chain.
//  - compute waves (w<4): barrier -> hGEMM -> cell -> h-store -> ack ->
//    flag -> xf reload -> xGEMM(t+1) -> barrier. No polls, no staging
//    loads, no ds_writes; vmem queue = 1 store.
// LDS safety (one barrier/step): DMA(t) into Hb[t&1] is gated on flags(t),
// which own-WG waves post at tail(t-1) AFTER hGEMM(t-1); readers of
// Hb[t&1] are hGEMM(t-2), complete by dependency before tail(t-2) ->
// HREADY(t-1) arrival. Same argument for Xb[(t+1)&1] (written step t,
// read at tail(t); prior read tail(t-2) precedes HREADY(t-1)). Producer
// protocol (store -> vmcnt(0) ack -> flag, sc0 sc1) unchanged from R6.
// Barrier counts: both paths hit 1 (prologue) + NSTEP barriers.
__global__ __launch_bounds__(320, 1)
void lstm_persistent(const float* __restrict__ x0, const float* __restrict__ x1,
                     const float* __restrict__ wih, const float* __restrict__ whh,
                     const float* __restrict__ bih, const float* __restrict__ bhh,
                     _Float16* __restrict__ hb, int* __restrict__ flg,
                     float* __restrict__ out) {
    __shared__ __align__(16) _Float16 Hb[2][16 * HPH];
    __shared__ __align__(16) float    Xb[2][16 * XPF];

    const int tid  = threadIdx.x;
    const int lane = tid & 63;
    const int w    = tid >> 6;       // wave 0..3 compute, 4 = sync
    const int quad = lane >> 4;
    const int l16  = lane & 15;
    const int igrp = blockIdx.x & 15;    // batch group (16 rows)
    const int jcg  = blockIdx.x >> 4;    // column group (32 H-cols)

    const float* xp  = (igrp < 8) ? x0 : x1;
    const int   brow = (igrp & 7) * 16;

    if (w == 4) {
        // ======================= SYNC / DMA wave =======================
        const int* fpoll = flg + igrp * 64 + lane;   // 64 wave-flags of my group
        int gaveup = 0;

        // prologue: stage x(0) -> Xb[0]
#pragma unroll
        for (int r = 0; r < 16; ++r) {
            const float* g = xp + (size_t)(brow + r) * SLEN * IDIM + lane * 4;
            __builtin_amdgcn_global_load_lds(
                (const AS1 void*)g, (AS3 void*)&Xb[0][r * XPF], 16, 0, 0);
        }
        asm volatile("s_waitcnt vmcnt(0)" ::: "memory");
        __builtin_amdgcn_sched_barrier(0);
        __builtin_amdgcn_s_barrier();    // P

#pragma unroll 1
        for (int t = 0; t < NSTEP; ++t) {
            // poll: all 64 producer waves signalled step t-1 (pure-load queue)
            if (t > 0 && !gaveup) {
                int it = 0;
                while (true) {
                    int f;
                    asm volatile("global_load_dword %0, %1, off sc0 sc1\n\t"
                                 "s_waitcnt vmcnt(0)"
                                 : "=&v"(f) : "v"(fpoll) : "memory");
                    if (__all(f >= t)) break;
                    __builtin_amdgcn_s_sleep(1);
                    if (++it > (1 << 20)) { gaveup = 1; break; }
                }
                __builtin_amdgcn_fence(__ATOMIC_ACQUIRE, "workgroup");
            }
            // h_{t-1} DMA -> Hb[t&1] (16 rows x 1KB, aux=17 = sc0|sc1)
            {
                const _Float16* hsrc = hb + (size_t)((t + 1) & 1) * (NROW * HDIM)
                                          + (size_t)(igrp * 16) * HDIM;
#pragma unroll
                for (int r = 0; r < 16; ++r) {
                    __builtin_amdgcn_global_load_lds(
                        (const AS1 void*)(hsrc + (size_t)r * HDIM + lane * 8),
                        (AS3 void*)&Hb[t & 1][r * HPH], 16, 0, 17);
                }
            }
            // x(t+1) DMA -> Xb[(t+1)&1]
            if (t < NSTEP - 1) {
#pragma unroll
                for (int r = 0; r < 16; ++r) {
                    const float* g = xp + (size_t)(brow + r) * SLEN * IDIM
                                        + (size_t)(t + 1) * IDIM + lane * 4;
                    __builtin_amdgcn_global_load_lds(
                        (const AS1 void*)g, (AS3 void*)&Xb[(t + 1) & 1][r * XPF],
                        16, 0, 0);
                }
            }
            asm volatile("s_waitcnt vmcnt(0)" ::: "memory");
            __builtin_amdgcn_sched_barrier(0);
            __builtin_amdgcn_s_barrier();   // HREADY(t)
        }
        return;
    }

    // ========================= COMPUTE waves =========================
    // W A-frags: global fp32 -> f16 regs, once
    const int q0  = l16 & 3, ccl = l16 >> 2;
    const int colb = jcg * 32 + w * 8 + ccl * 2;
    const int gc0 = q0 * HDIM + colb;
    const int gc1 = gc0 + 1;
    half8 wf0[24], wf1[24];
#pragma unroll
    for (int kk = 0; kk < 24; ++kk) {
        int k0 = kk * 32 + quad * 8;
        const float* sA = (k0 < IDIM) ? wih + (size_t)gc0 * IDIM + k0
                                      : whh + (size_t)gc0 * HDIM + (k0 - IDIM);
        const float* sB = (k0 < IDIM) ? wih + (size_t)gc1 * IDIM + k0
                                      : whh + (size_t)gc1 * HDIM + (k0 - IDIM);
        wf0[kk] = cvt8(*(const float4*)sA, *(const float4*)(sA + 4));
        wf1[kk] = cvt8(*(const float4*)sB, *(const float4*)(sB + 4));
    }

    float bias0[4], bias1[4];
#pragma unroll
    for (int q = 0; q < 4; ++q) {
        int g0 = q * HDIM + jcg * 32 + w * 8 + quad * 2;
        bias0[q] = bih[g0] + bhh[g0];
        bias1[q] = bih[g0 + 1] + bhh[g0 + 1];
    }

    const int grow = igrp * 16 + l16;     // my batch row (global)
    const int cc0  = jcg * 32 + w * 8 + quad * 2;   // my H-cols (cc0, cc0+1)
    int*      fmine = flg + igrp * 64 + jcg * 4 + w;

    float c0 = 0.f, c1 = 0.f;

    __builtin_amdgcn_s_barrier();    // P: Xb[0] staged by sync wave

    // xf(0) + x-GEMM(0)
    half8 xf[8];
    f32x4 acc0, acc1;
    {
        const float* xb = &Xb[0][l16 * XPF + quad * 8];
#pragma unroll
        for (int kk = 0; kk < 8; ++kk)
            xf[kk] = cvt8(*(const float4*)(xb + kk * 32),
                          *(const float4*)(xb + kk * 32 + 4));
        acc0 = f32x4{bias0[0], bias0[1], bias0[2], bias0[3]};
        acc1 = f32x4{bias1[0], bias1[1], bias1[2], bias1[3]};
#pragma unroll
        for (int kk = 0; kk < 8; ++kk) {
            acc0 = __builtin_amdgcn_mfma_f32_16x16x32_f16(wf0[kk], xf[kk], acc0, 0, 0, 0);
            acc1 = __builtin_amdgcn_mfma_f32_16x16x32_f16(wf1[kk], xf[kk], acc1, 0, 0, 0);
        }
    }

#pragma unroll 1
    for (int t = 0; t < NSTEP; ++t) {
        __builtin_amdgcn_s_barrier();   // HREADY(t): Hb[t&1] + Xb[(t+1)&1] staged

        // h-part GEMM (K=512), 4 accumulator chains
        {
            const _Float16* abh = &Hb[t & 1][l16 * HPH + quad * 8];
            f32x4 b0 = {0.f, 0.f, 0.f, 0.f}, b1 = {0.f, 0.f, 0.f, 0.f};
#pragma unroll
            for (int kk = 0; kk < 16; kk += 2) {
                half8 bfa = *(const half8*)(abh + kk * 32);
                half8 bfb = *(const half8*)(abh + (kk + 1) * 32);
                acc0 = __builtin_amdgcn_mfma_f32_16x16x32_f16(wf0[8 + kk], bfa, acc0, 0, 0, 0);
                b0   = __builtin_amdgcn_mfma_f32_16x16x32_f16(wf0[9 + kk], bfb, b0, 0, 0, 0);
                acc1 = __builtin_amdgcn_mfma_f32_16x16x32_f16(wf1[8 + kk], bfa, acc1, 0, 0, 0);
                b1   = __builtin_amdgcn_mfma_f32_16x16x32_f16(wf1[9 + kk], bfb, b1, 0, 0, 0);
            }
            acc0 += b0;
            acc1 += b1;
        }

        // cell update (regs 0..3 = i,f,g,o), fp32
        float i0 = sigm(acc0[0]), f0g = sigm(acc0[1]), g0 = tanh_f(acc0[2]), o0g = sigm(acc0[3]);
        c0 = f0g * c0 + i0 * g0;
        float h0 = o0g * tanh_f(c0);
        float i1 = sigm(acc1[0]), f1g = sigm(acc1[1]), g1 = tanh_f(acc1[2]), o1g = sigm(acc1[3]);
        c1 = f1g * c1 + i1 * g1;
        float h1 = o1g * tanh_f(c1);

        if (t < NSTEP - 1) {
            // h store -> ack (queue = this store only) -> flag
            _Float16* hd = hb + (size_t)(t & 1) * (NROW * HDIM) + (size_t)grow * HDIM;
            hu u0; u0.h = (_Float16)h0;
            hu u1; u1.h = (_Float16)h1;
            unsigned int hp = (unsigned int)u0.u | ((unsigned int)u1.u << 16);
            asm volatile("global_store_dword %0, %1, off sc0 sc1"
                         :: "v"((int*)(hd + cc0)), "v"(hp) : "memory");
            __builtin_amdgcn_sched_barrier(0);
            asm volatile("s_waitcnt vmcnt(0)" ::: "memory");
            __builtin_amdgcn_sched_barrier(0);
            if (lane == 0) {
                int fv = t + 1;
                asm volatile("global_store_dword %0, %1, off sc0 sc1"
                             :: "v"(fmine), "v"(fv) : "memory");
            }
            // xf reload + x-GEMM(t+1): off the chain (sync wave is polling/DMAing)
            const float* xb = &Xb[(t + 1) & 1][l16 * XPF + quad * 8];
#pragma unroll
            for (int kk = 0; kk < 8; ++kk)
                xf[kk] = cvt8(*(const float4*)(xb + kk * 32),
                              *(const float4*)(xb + kk * 32 + 4));
            acc0 = f32x4{bias0[0], bias0[1], bias0[2], bias0[3]};
            acc1 = f32x4{bias1[0], bias1[1], bias1[2], bias1[3]};
#pragma unroll
            for (int kk = 0; kk < 8; ++kk) {
                acc0 = __builtin_amdgcn_mfma_f32_16x16x32_f16(wf0[kk], xf[kk], acc0, 0, 0, 0);
                acc1 = __builtin_amdgcn_mfma_f32_16x16x32_f16(wf1[kk], xf[kk], acc1, 0, 0, 0);
            }
        } else {
            float2 ov; ov.x = h0; ov.y = h1;
            *(float2*)(out + (size_t)grow * HDIM + cc0) = ov;
        }
    }
}

extern "C" void kernel_launch(void* const* d_in, const int* in_sizes, int n_in,
                              void* d_out, int out_size, void* d_ws, size_t ws_size,
                              hipStream_t stream) {
    const float* x0  = (const float*)d_in[0];   // [128,512,256] fp32
    const float* x1  = (const float*)d_in[1];
    const float* wih = (const float*)d_in[2];   // [2048,256]
    const float* whh = (const float*)d_in[3];   // [2048,512]
    const float* bih = (const float*)d_in[4];   // [2048]
    const float* bhh = (const float*)d_in[5];   // [2048]

    // ws: h ping-pong (2 x 256 KB f16) + per-(group,wave) flags (16 x 64 ints)
    _Float16* hb = (_Float16*)d_ws;
    int* flg = (int*)((char*)d_ws + (size_t)2 * NROW * HDIM * sizeof(_Float16));
    size_t zbytes = (size_t)2 * NROW * HDIM * sizeof(_Float16)
                  + (size_t)NGRP * 64 * sizeof(int);
    hipMemsetAsync(d_ws, 0, zbytes, stream);   // zero h_{-1} + flags

    lstm_persistent<<<dim3(256), dim3(320), 0, stream>>>(
        x0, x1, wih, whh, bih, bhh, hb, flg, (float*)d_out);
}